// Round 5
// baseline (455.565 us; speedup 1.0000x reference)
//
#include <hip/hip_runtime.h>

typedef short s16x8 __attribute__((ext_vector_type(8)));
typedef short s16x4 __attribute__((ext_vector_type(4)));
typedef float f32x4 __attribute__((ext_vector_type(4)));

static __device__ __forceinline__ unsigned short f2bf(float f) {
  unsigned u = __float_as_uint(f);
  u += 0x7fff + ((u >> 16) & 1);  // round-to-nearest-even
  return (unsigned short)(u >> 16);
}
static __device__ __forceinline__ float bf2f(unsigned short h) {
  return __uint_as_float(((unsigned)h) << 16);
}

// ---------------- CSR build ----------------

static __global__ void k_init(int* cntT, int* cntE, int n) {
  int i = blockIdx.x * blockDim.x + threadIdx.x;
  if (i < n) { cntT[i] = 0; cntE[i] = 0; }
}

// counts + per-edge rank (rank = old count value, from the atomic return)
static __global__ void k_count(const int* __restrict__ tcol, const int* __restrict__ ecol,
                               int* __restrict__ cntT, int* __restrict__ cntE,
                               int* __restrict__ rankT, int* __restrict__ rankE, int E) {
  int e = blockIdx.x * blockDim.x + threadIdx.x;
  if (e < E) {
    rankT[e] = atomicAdd(&cntT[tcol[e]], 1);
    rankE[e] = atomicAdd(&cntE[ecol[e]], 1);
  }
}

// 3-phase exclusive scan over both count arrays (grid.y selects array)
static __global__ __launch_bounds__(256) void k_scanA(
    const int* __restrict__ cntT, const int* __restrict__ cntE,
    int* __restrict__ bsum, int n, int nb) {
  const int* cnt = blockIdx.y ? cntE : cntT;
  int tid = threadIdx.x;
  int base = blockIdx.x * 1024 + tid * 4;
  int s = 0;
#pragma unroll
  for (int q = 0; q < 4; ++q) { int i = base + q; if (i < n) s += cnt[i]; }
  __shared__ int red[256];
  red[tid] = s;
  __syncthreads();
  for (int off = 128; off > 0; off >>= 1) {
    if (tid < off) red[tid] += red[tid + off];
    __syncthreads();
  }
  if (tid == 0) bsum[blockIdx.y * nb + blockIdx.x] = red[0];
}

static __global__ void k_scanB(int* bsum, int* ptrT, int* ptrE, int nb, int n) {
  int a = threadIdx.x;
  if (a > 1) return;
  int* bs = bsum + a * nb;
  int run = 0;
  for (int i = 0; i < nb; ++i) { int c = bs[i]; bs[i] = run; run += c; }
  (a ? ptrE : ptrT)[n] = run;
}

static __global__ __launch_bounds__(256) void k_scanC(
    const int* __restrict__ cntT, const int* __restrict__ cntE,
    const int* __restrict__ bsum, int* __restrict__ ptrT, int* __restrict__ ptrE,
    int n, int nb) {
  const int* cnt = blockIdx.y ? cntE : cntT;
  int* ptr = blockIdx.y ? ptrE : ptrT;
  int tid = threadIdx.x;
  int pre = bsum[blockIdx.y * nb + blockIdx.x];
  int base = blockIdx.x * 1024 + tid * 4;
  int v[4];
  int s = 0;
#pragma unroll
  for (int q = 0; q < 4; ++q) { int i = base + q; v[q] = (i < n) ? cnt[i] : 0; s += v[q]; }
  __shared__ int red[256];
  red[tid] = s;
  __syncthreads();
  for (int off = 1; off < 256; off <<= 1) {
    int t = (tid >= off) ? red[tid - off] : 0;
    __syncthreads();
    red[tid] += t;
    __syncthreads();
  }
  int run = pre + (tid ? red[tid - 1] : 0);
#pragma unroll
  for (int q = 0; q < 4; ++q) {
    int i = base + q;
    if (i < n) ptr[i] = run;
    run += v[q];
  }
}

// atomic-free fill: slot = ptr[col] + rank
static __global__ void k_fill(const int* __restrict__ trow, const int* __restrict__ tcol,
                              const int* __restrict__ erow, const int* __restrict__ ecol,
                              const float* __restrict__ ew,
                              const int* __restrict__ ptrT, const int* __restrict__ ptrE,
                              const int* __restrict__ rankT, const int* __restrict__ rankE,
                              int* __restrict__ srcT, int2* __restrict__ srcwE, int E) {
  int e = blockIdx.x * blockDim.x + threadIdx.x;
  if (e >= E) return;
  srcT[ptrT[tcol[e]] + rankT[e]] = trow[e];
  int2 p;
  p.x = erow[e];
  p.y = __float_as_int(ew[e]);
  srcwE[ptrE[ecol[e]] + rankE[e]] = p;
}

// dinvT from counts; dinvE from CSR segment-sum of ew
static __global__ void k_dinv2(const int* __restrict__ cntT, const int2* __restrict__ srcwE,
                               const int* __restrict__ ptrE,
                               float* __restrict__ dinvT, float* __restrict__ dinvE, int n) {
  int i = blockIdx.x * blockDim.x + threadIdx.x;
  if (i >= n) return;
  dinvT[i] = rsqrtf((float)cntT[i] + 1.0f);
  float s = 1.0f;  // self loop
  int e = ptrE[i + 1];
  for (int j = ptrE[i]; j < e; ++j) s += __int_as_float(srcwE[j].y);
  dinvE[i] = rsqrtf(s);
}

// ---------------- W1 pre-transpose + bf16 split ----------------

static __global__ void k_cvtW(const float* __restrict__ W, unsigned short* __restrict__ Wh,
                              unsigned short* __restrict__ Wl, int K, int Nc) {
  int t = blockIdx.x * blockDim.x + threadIdx.x;
  if (t >= K * Nc) return;
  int k = t / Nc, c = t - k * Nc;
  float v = W[t];
  unsigned short hi = f2bf(v);
  Wh[(size_t)c * K + k] = hi;
  Wl[(size_t)c * K + k] = f2bf(v - bf2f(hi));
}

// ---------------- MFMA split-bf16 GEMM: C[M][128] = A[M][K] @ B[K][128] ----------------
// 64-row tiles (782 blocks -> ~3 blocks/CU), B fragments read straight from
// L2-resident Bh/Bl (no LDS for B), register-staged A prefetch.

#define PADU 36  // LDS row stride in ushort (72 B): 16 distinct bank starts for b128 reads

static __global__ __launch_bounds__(256) void k_gemm_mfma_split(
    const float* __restrict__ A, const unsigned short* __restrict__ Bh,
    const unsigned short* __restrict__ Bl, float* __restrict__ C, int M, int K) {
  __shared__ __align__(16) unsigned short Ah[64][PADU];
  __shared__ __align__(16) unsigned short Al[64][PADU];
  int tid = threadIdx.x;
  int lane = tid & 63, wid = tid >> 6;
  int wr = wid >> 1, wc = wid & 1;        // wave = 32 rows x 64 cols
  int l15 = lane & 15, l4 = lane >> 4;
  int brow = blockIdx.x * 64;
  f32x4 acc[2][4] = {};

  // register prefetch of k-tile 0
  float4 v[2];
#pragma unroll
  for (int q = 0; q < 2; ++q) {
    int idx = tid + q * 256;
    int r = idx >> 3, c4 = (idx & 7) * 4;
    int gr = brow + r;
    v[q] = (gr < M) ? *(const float4*)&A[(size_t)gr * K + c4]
                    : make_float4(0.f, 0.f, 0.f, 0.f);
  }

  for (int k0 = 0; k0 < K; k0 += 32) {
    __syncthreads();
    // convert + store the prefetched tile
#pragma unroll
    for (int q = 0; q < 2; ++q) {
      int idx = tid + q * 256;
      int r = idx >> 3, c4 = (idx & 7) * 4;
      float4 w = v[q];
      unsigned short h0 = f2bf(w.x), h1 = f2bf(w.y), h2 = f2bf(w.z), h3 = f2bf(w.w);
      s16x4 hv = {(short)h0, (short)h1, (short)h2, (short)h3};
      s16x4 lv = {(short)f2bf(w.x - bf2f(h0)), (short)f2bf(w.y - bf2f(h1)),
                  (short)f2bf(w.z - bf2f(h2)), (short)f2bf(w.w - bf2f(h3))};
      *(s16x4*)&Ah[r][c4] = hv;
      *(s16x4*)&Al[r][c4] = lv;
    }
    // issue next tile's global loads (overlaps with MFMA below)
    if (k0 + 32 < K) {
#pragma unroll
      for (int q = 0; q < 2; ++q) {
        int idx = tid + q * 256;
        int r = idx >> 3, c4 = (idx & 7) * 4;
        int gr = brow + r;
        v[q] = (gr < M) ? *(const float4*)&A[(size_t)gr * K + k0 + 32 + c4]
                        : make_float4(0.f, 0.f, 0.f, 0.f);
      }
    }
    __syncthreads();

    s16x8 afh[2], afl[2];
#pragma unroll
    for (int m = 0; m < 2; ++m) {
      int r = wr * 32 + m * 16 + l15;
      afh[m] = *(const s16x8*)&Ah[r][l4 * 8];
      afl[m] = *(const s16x8*)&Al[r][l4 * 8];
    }
    s16x8 bfh[4], bfl[4];
#pragma unroll
    for (int n = 0; n < 4; ++n) {
      int c = wc * 64 + n * 16 + l15;
      bfh[n] = *(const s16x8*)&Bh[(size_t)c * K + k0 + l4 * 8];
      bfl[n] = *(const s16x8*)&Bl[(size_t)c * K + k0 + l4 * 8];
    }
#pragma unroll
    for (int m = 0; m < 2; ++m)
#pragma unroll
      for (int n = 0; n < 4; ++n) {
        acc[m][n] = __builtin_amdgcn_mfma_f32_16x16x32_bf16(afh[m], bfh[n], acc[m][n], 0, 0, 0);
        acc[m][n] = __builtin_amdgcn_mfma_f32_16x16x32_bf16(afl[m], bfh[n], acc[m][n], 0, 0, 0);
        acc[m][n] = __builtin_amdgcn_mfma_f32_16x16x32_bf16(afh[m], bfl[n], acc[m][n], 0, 0, 0);
      }
  }
#pragma unroll
  for (int m = 0; m < 2; ++m) {
    int rbase = brow + wr * 32 + m * 16 + l4 * 4;
#pragma unroll
    for (int n = 0; n < 4; ++n) {
      int c = wc * 64 + n * 16 + l15;
#pragma unroll
      for (int j = 0; j < 4; ++j) {
        int r = rbase + j;
        if (r < M) C[(size_t)r * 128 + c] = acc[m][n][j];
      }
    }
  }
}

// ---------------- gather-aggregate (CSR), float4-vectorized ----------------
// out[node] = (sum_j w_j * H[src_j] + dinv[node]*Hpre[node]) * dinv[node] + bias
// unweighted: w_j = dinv[src]; weighted: w_j = dinv[src]*ew_j

template <int F, bool RELU, bool WEIGHTED>
static __global__ __launch_bounds__(256) void k_gather4(
    const float* __restrict__ H, const int* __restrict__ rowptr,
    const int* __restrict__ src, const int2* __restrict__ srcw,
    const float* __restrict__ dinv, const float* __restrict__ Hpre,
    const float* __restrict__ bias, float* __restrict__ out, int n) {
  const int L = F / 4;
  int node = blockIdx.x * (256 / L) + threadIdx.x / L;
  if (node >= n) return;
  int f4 = (threadIdx.x % L) * 4;
  float d = dinv[node];
  float4 hp = *(const float4*)&Hpre[(size_t)node * F + f4];
  float ax = hp.x * d, ay = hp.y * d, az = hp.z * d, aw = hp.w * d;
  int j = rowptr[node], e = rowptr[node + 1];
  for (; j + 1 < e; j += 2) {
    int r0, r1;
    float w0, w1;
    if (WEIGHTED) {
      int2 a = srcw[j], b = srcw[j + 1];
      r0 = a.x; r1 = b.x;
      w0 = dinv[r0] * __int_as_float(a.y);
      w1 = dinv[r1] * __int_as_float(b.y);
    } else {
      r0 = src[j]; r1 = src[j + 1];
      w0 = dinv[r0]; w1 = dinv[r1];
    }
    float4 v0 = *(const float4*)&H[(size_t)r0 * F + f4];
    float4 v1 = *(const float4*)&H[(size_t)r1 * F + f4];
    ax += v0.x * w0 + v1.x * w1;
    ay += v0.y * w0 + v1.y * w1;
    az += v0.z * w0 + v1.z * w1;
    aw += v0.w * w0 + v1.w * w1;
  }
  if (j < e) {
    int r;
    float wj;
    if (WEIGHTED) { int2 a = srcw[j]; r = a.x; wj = dinv[r] * __int_as_float(a.y); }
    else { r = src[j]; wj = dinv[r]; }
    float4 v = *(const float4*)&H[(size_t)r * F + f4];
    ax += v.x * wj; ay += v.y * wj; az += v.z * wj; aw += v.w * wj;
  }
  float bx = 0, by = 0, bz = 0, bw = 0;
  if (bias) { float4 bb = *(const float4*)&bias[f4]; bx = bb.x; by = bb.y; bz = bb.z; bw = bb.w; }
  ax = ax * d + bx; ay = ay * d + by; az = az * d + bz; aw = aw * d + bw;
  if (RELU) { ax = fmaxf(ax, 0.f); ay = fmaxf(ay, 0.f); az = fmaxf(az, 0.f); aw = fmaxf(aw, 0.f); }
  float4 o; o.x = ax; o.y = ay; o.z = az; o.w = aw;
  *(float4*)&out[(size_t)node * F + f4] = o;
}

// ---------------- fp32 tiled GEMM (small N: conv2 + heads) ----------------

static __global__ __launch_bounds__(256) void k_gemm(
    const float* __restrict__ A, const float* __restrict__ B,
    const float* __restrict__ bias, float* __restrict__ C,
    int M, int N, int K) {
  const int BM = 64, BN = 64, BK = 16;
  __shared__ float As[BK][BM + 4];
  __shared__ float Bs[BK][BN + 4];
  int tid = threadIdx.x;
  int tr = tid >> 4, tc = tid & 15;
  int brow = blockIdx.y * BM, bcol = blockIdx.x * BN;
  float acc[4][4] = {};
  for (int k0 = 0; k0 < K; k0 += BK) {
#pragma unroll
    for (int i = tid; i < BM * BK; i += 256) {
      int m = i >> 4, kk = i & 15;
      int gr = brow + m;
      As[kk][m] = (gr < M) ? A[(size_t)gr * K + k0 + kk] : 0.f;
    }
#pragma unroll
    for (int i = tid; i < BK * BN; i += 256) {
      int kk = i >> 6, n = i & 63;
      int gc = bcol + n;
      Bs[kk][n] = (gc < N) ? B[(size_t)(k0 + kk) * N + gc] : 0.f;
    }
    __syncthreads();
#pragma unroll
    for (int kk = 0; kk < BK; ++kk) {
      float a[4], b[4];
#pragma unroll
      for (int i = 0; i < 4; ++i) a[i] = As[kk][tr * 4 + i];
#pragma unroll
      for (int j = 0; j < 4; ++j) b[j] = Bs[kk][tc * 4 + j];
#pragma unroll
      for (int i = 0; i < 4; ++i)
#pragma unroll
        for (int j = 0; j < 4; ++j) acc[i][j] += a[i] * b[j];
    }
    __syncthreads();
  }
#pragma unroll
  for (int i = 0; i < 4; ++i) {
    int r = brow + tr * 4 + i;
    if (r >= M) continue;
#pragma unroll
    for (int j = 0; j < 4; ++j) {
      int c = bcol + tc * 4 + j;
      if (c < N) C[(size_t)r * N + c] = acc[i][j] + (bias ? bias[c] : 0.f);
    }
  }
}

// ---------------- log-softmax over 40 classes, in place ----------------

static __global__ void k_logsoftmax40(float* __restrict__ X, int n) {
  int i = blockIdx.x * blockDim.x + threadIdx.x;
  if (i >= n) return;
  float4 v[10];
#pragma unroll
  for (int q = 0; q < 10; ++q) v[q] = *(const float4*)&X[(size_t)i * 40 + q * 4];
  float m = -1e30f;
#pragma unroll
  for (int q = 0; q < 10; ++q)
    m = fmaxf(m, fmaxf(fmaxf(v[q].x, v[q].y), fmaxf(v[q].z, v[q].w)));
  float s = 0.f;
#pragma unroll
  for (int q = 0; q < 10; ++q)
    s += expf(v[q].x - m) + expf(v[q].y - m) + expf(v[q].z - m) + expf(v[q].w - m);
  float ls = logf(s) + m;
#pragma unroll
  for (int q = 0; q < 10; ++q) {
    float4 o; o.x = v[q].x - ls; o.y = v[q].y - ls; o.z = v[q].z - ls; o.w = v[q].w - ls;
    *(float4*)&X[(size_t)i * 40 + q * 4] = o;
  }
}

// ---------------- link prediction ----------------

static __global__ __launch_bounds__(256) void k_linkpred4(
    const float* __restrict__ H2, const int* __restrict__ pos,
    const int* __restrict__ neg, float* __restrict__ res, int Elp) {
  int t = blockIdx.x * 256 + threadIdx.x;
  int e = t >> 4, f4 = (t & 15) * 4;
  if (e >= 2 * Elp) return;
  int a, b;
  if (e < Elp) { a = pos[e]; b = pos[Elp + e]; }
  else { int e2 = e - Elp; a = neg[e2]; b = neg[Elp + e2]; }
  float4 va = *(const float4*)&H2[(size_t)a * 64 + f4];
  float4 vb = *(const float4*)&H2[(size_t)b * 64 + f4];
  float p = va.x * vb.x + va.y * vb.y + va.z * vb.z + va.w * vb.w;
  p += __shfl_xor(p, 1);
  p += __shfl_xor(p, 2);
  p += __shfl_xor(p, 4);
  p += __shfl_xor(p, 8);
  if ((t & 15) == 0) res[e] = p;
}

// ---------------- launch ----------------

extern "C" void kernel_launch(void* const* d_in, const int* in_sizes, int n_in,
                              void* d_out, int out_size, void* d_ws, size_t ws_size,
                              hipStream_t stream) {
  const float* x    = (const float*)d_in[0];
  const int*   tp   = (const int*)d_in[1];
  const int*   ei   = (const int*)d_in[2];
  const float* ew   = (const float*)d_in[3];
  const int*   pos  = (const int*)d_in[4];
  const int*   neg  = (const int*)d_in[5];
  const float* W1   = (const float*)d_in[6];
  const float* b1   = (const float*)d_in[7];
  const float* W2   = (const float*)d_in[8];
  const float* b2   = (const float*)d_in[9];
  const float* Wattr= (const float*)d_in[10];
  const float* battr= (const float*)d_in[11];
  const float* Watt = (const float*)d_in[12];
  const float* batt = (const float*)d_in[13];

  const int N   = in_sizes[0] / 512;  // 50000
  const int EMP = in_sizes[1] / 2;    // 800000
  const int ELP = in_sizes[4] / 2;    // 250000
  const int NB  = (N + 1023) / 1024;  // scan blocks per array

  // workspace layout (4B units, 16B-aligned regions)
  float* ws = (float*)d_ws;
  float* dinvT = ws;                          // N
  float* dinvE = dinvT + N;                   // N
  int* rowptrT = (int*)(dinvE + N);           // N+1 (+pad)
  int* rowptrE = rowptrT + (N + 4);           // N+1 (+pad)
  int* srcT    = rowptrE + (N + 4);           // EMP
  int2* srcwE  = (int2*)(srcT + EMP);         // EMP int2
  int* bsum    = (int*)(srcwE + EMP);         // 2*NB (+pad)
  unsigned short* W1h = (unsigned short*)(bsum + 128);  // 512*128 bf16
  unsigned short* W1l = W1h + 512 * 128;                // 512*128 bf16
  float* bufA  = (float*)(W1l + 512 * 128);   // N*128
  float* bufB  = bufA + (size_t)N * 128;      // N*128
  float* bufC  = bufB + (size_t)N * 128;      // N*64
  // overlays (dead before their hosts are written):
  int* rankT = (int*)bufA;                    // EMP (dead after k_fill; bufA written later)
  int* rankE = rankT + EMP;                   // EMP
  int* cntT  = (int*)bufB;                    // N (dead after k_dinv2; bufB written later)
  int* cntE  = cntT + N;                      // N

  float* out_res  = (float*)d_out;
  float* out_attr = out_res + 2 * (size_t)ELP;
  float* out_att  = out_attr + (size_t)N * 40;

  dim3 b256(256);
  int gN = (N + 255) / 256;
  int gE = (EMP + 255) / 256;

  // CSR build + norms (+ W1 convert, independent)
  k_init<<<gN, b256, 0, stream>>>(cntT, cntE, N);
  k_cvtW<<<(512 * 128 + 255) / 256, b256, 0, stream>>>(W1, W1h, W1l, 512, 128);
  k_count<<<gE, b256, 0, stream>>>(tp + EMP, ei + EMP, cntT, cntE, rankT, rankE, EMP);
  {
    dim3 gs(NB, 2);
    k_scanA<<<gs, b256, 0, stream>>>(cntT, cntE, bsum, N, NB);
    k_scanB<<<1, 64, 0, stream>>>(bsum, rowptrT, rowptrE, NB, N);
    k_scanC<<<gs, b256, 0, stream>>>(cntT, cntE, bsum, rowptrT, rowptrE, N, NB);
  }
  k_fill<<<gE, b256, 0, stream>>>(tp, tp + EMP, ei, ei + EMP, ew,
                                  rowptrT, rowptrE, rankT, rankE, srcT, srcwE, EMP);
  k_dinv2<<<gN, b256, 0, stream>>>(cntT, srcwE, rowptrE, dinvT, dinvE, N);

  // conv1: h1_pre = x @ W1 (MFMA split-bf16) ; h = relu(Agg_T(h1_pre) + b1)
  k_gemm_mfma_split<<<(N + 63) / 64, b256, 0, stream>>>(x, W1h, W1l, bufA, N, 512);
  k_gather4<128, true, false><<<(N + 7) / 8, b256, 0, stream>>>(
      bufA, rowptrT, srcT, nullptr, dinvT, bufA, b1, bufB, N);

  // conv2: h2_pre = h @ W2 ; h2 = Agg_T(h2_pre) + b2
  {
    dim3 grid(1, (N + 63) / 64);
    k_gemm<<<grid, b256, 0, stream>>>(bufB, W2, nullptr, bufA, N, 64, 128);
  }
  k_gather4<64, false, false><<<(N + 15) / 16, b256, 0, stream>>>(
      bufA, rowptrT, srcT, nullptr, dinvT, bufA, b2, bufC, N);

  // conv3/4 share aggregation: agg3 = Agg_E(h2) into bufA
  k_gather4<64, false, true><<<(N + 15) / 16, b256, 0, stream>>>(
      bufC, rowptrE, nullptr, srcwE, dinvE, bufC, nullptr, bufA, N);

  // heads
  {
    dim3 grid(1, (N + 63) / 64);
    k_gemm<<<grid, b256, 0, stream>>>(bufA, Wattr, battr, out_attr, N, 40, 64);
    k_gemm<<<grid, b256, 0, stream>>>(bufA, Watt, batt, out_att, N, 40, 64);
  }
  k_logsoftmax40<<<gN, b256, 0, stream>>>(out_attr, N);
  k_logsoftmax40<<<gN, b256, 0, stream>>>(out_att, N);

  // link prediction (h2 = bufC)
  k_linkpred4<<<(2 * ELP * 16 + 255) / 256, b256, 0, stream>>>(bufC, pos, neg, out_res, ELP);
}

// Round 6
// 435.042 us; speedup vs baseline: 1.0472x; 1.0472x over previous
//
#include <hip/hip_runtime.h>

typedef short s16x8 __attribute__((ext_vector_type(8)));
typedef short s16x4 __attribute__((ext_vector_type(4)));
typedef float f32x4 __attribute__((ext_vector_type(4)));

static __device__ __forceinline__ unsigned short f2bf(float f) {
  unsigned u = __float_as_uint(f);
  u += 0x7fff + ((u >> 16) & 1);  // round-to-nearest-even
  return (unsigned short)(u >> 16);
}
static __device__ __forceinline__ float bf2f(unsigned short h) {
  return __uint_as_float(((unsigned)h) << 16);
}

// ---------------- CSR build ----------------

static __global__ void k_init(int* cntT, int* cntE, int n) {
  int i = blockIdx.x * blockDim.x + threadIdx.x;
  if (i < n) { cntT[i] = 0; cntE[i] = 0; }
}

// counts + per-edge rank (rank = old count value, from the atomic return)
static __global__ void k_count(const int* __restrict__ tcol, const int* __restrict__ ecol,
                               int* __restrict__ cntT, int* __restrict__ cntE,
                               int* __restrict__ rankT, int* __restrict__ rankE, int E) {
  int e = blockIdx.x * blockDim.x + threadIdx.x;
  if (e < E) {
    rankT[e] = atomicAdd(&cntT[tcol[e]], 1);
    rankE[e] = atomicAdd(&cntE[ecol[e]], 1);
  }
}

// 3-phase exclusive scan over both count arrays (grid.y selects array)
static __global__ __launch_bounds__(256) void k_scanA(
    const int* __restrict__ cntT, const int* __restrict__ cntE,
    int* __restrict__ bsum, int n, int nb) {
  const int* cnt = blockIdx.y ? cntE : cntT;
  int tid = threadIdx.x;
  int base = blockIdx.x * 1024 + tid * 4;
  int s = 0;
#pragma unroll
  for (int q = 0; q < 4; ++q) { int i = base + q; if (i < n) s += cnt[i]; }
  __shared__ int red[256];
  red[tid] = s;
  __syncthreads();
  for (int off = 128; off > 0; off >>= 1) {
    if (tid < off) red[tid] += red[tid + off];
    __syncthreads();
  }
  if (tid == 0) bsum[blockIdx.y * nb + blockIdx.x] = red[0];
}

static __global__ void k_scanB(int* bsum, int* ptrT, int* ptrE, int nb, int n) {
  int a = threadIdx.x;
  if (a > 1) return;
  int* bs = bsum + a * nb;
  int run = 0;
  for (int i = 0; i < nb; ++i) { int c = bs[i]; bs[i] = run; run += c; }
  (a ? ptrE : ptrT)[n] = run;
}

static __global__ __launch_bounds__(256) void k_scanC(
    const int* __restrict__ cntT, const int* __restrict__ cntE,
    const int* __restrict__ bsum, int* __restrict__ ptrT, int* __restrict__ ptrE,
    int n, int nb) {
  const int* cnt = blockIdx.y ? cntE : cntT;
  int* ptr = blockIdx.y ? ptrE : ptrT;
  int tid = threadIdx.x;
  int pre = bsum[blockIdx.y * nb + blockIdx.x];
  int base = blockIdx.x * 1024 + tid * 4;
  int v[4];
  int s = 0;
#pragma unroll
  for (int q = 0; q < 4; ++q) { int i = base + q; v[q] = (i < n) ? cnt[i] : 0; s += v[q]; }
  __shared__ int red[256];
  red[tid] = s;
  __syncthreads();
  for (int off = 1; off < 256; off <<= 1) {
    int t = (tid >= off) ? red[tid - off] : 0;
    __syncthreads();
    red[tid] += t;
    __syncthreads();
  }
  int run = pre + (tid ? red[tid - 1] : 0);
#pragma unroll
  for (int q = 0; q < 4; ++q) {
    int i = base + q;
    if (i < n) ptr[i] = run;
    run += v[q];
  }
}

// atomic-free fill: slot = ptr[col] + rank
static __global__ void k_fill(const int* __restrict__ trow, const int* __restrict__ tcol,
                              const int* __restrict__ erow, const int* __restrict__ ecol,
                              const float* __restrict__ ew,
                              const int* __restrict__ ptrT, const int* __restrict__ ptrE,
                              const int* __restrict__ rankT, const int* __restrict__ rankE,
                              int* __restrict__ srcT, int2* __restrict__ srcwE, int E) {
  int e = blockIdx.x * blockDim.x + threadIdx.x;
  if (e >= E) return;
  srcT[ptrT[tcol[e]] + rankT[e]] = trow[e];
  int2 p;
  p.x = erow[e];
  p.y = __float_as_int(ew[e]);
  srcwE[ptrE[ecol[e]] + rankE[e]] = p;
}

// dinvT from counts; dinvE from CSR segment-sum of ew
static __global__ void k_dinv2(const int* __restrict__ cntT, const int2* __restrict__ srcwE,
                               const int* __restrict__ ptrE,
                               float* __restrict__ dinvT, float* __restrict__ dinvE, int n) {
  int i = blockIdx.x * blockDim.x + threadIdx.x;
  if (i >= n) return;
  dinvT[i] = rsqrtf((float)cntT[i] + 1.0f);
  float s = 1.0f;  // self loop
  int e = ptrE[i + 1];
  for (int j = ptrE[i]; j < e; ++j) s += __int_as_float(srcwE[j].y);
  dinvE[i] = rsqrtf(s);
}

// ---------------- W1 -> k-tiled transposed bf16 split ----------------
// Output layout: Wh/Wl[kt][c][kk]  (kt = k/32, kk = k%32, c = 0..127)

static __global__ void k_cvtW(const float* __restrict__ W, unsigned short* __restrict__ Wh,
                              unsigned short* __restrict__ Wl, int K, int Nc) {
  int t = blockIdx.x * blockDim.x + threadIdx.x;
  if (t >= K * Nc) return;
  int k = t / Nc, c = t - k * Nc;
  float v = W[t];
  unsigned short hi = f2bf(v);
  size_t o = (size_t)(k >> 5) * (Nc * 32) + c * 32 + (k & 31);
  Wh[o] = hi;
  Wl[o] = f2bf(v - bf2f(hi));
}

// ---------------- MFMA split-bf16 GEMM: C[M][128] = A[M][K] @ B[K][128] ----------------
// 64-row tiles; B fragments from L2 in k-tiled coalesced layout, register-
// pipelined one k-tile ahead (A global->LDS also one tile ahead).

#define PADU 36  // LDS row stride in ushort (72 B)

static __global__ __launch_bounds__(256) void k_gemm_mfma_split(
    const float* __restrict__ A, const unsigned short* __restrict__ Bh,
    const unsigned short* __restrict__ Bl, float* __restrict__ C, int M, int K) {
  __shared__ __align__(16) unsigned short Ah[64][PADU];
  __shared__ __align__(16) unsigned short Al[64][PADU];
  int tid = threadIdx.x;
  int lane = tid & 63, wid = tid >> 6;
  int wr = wid >> 1, wc = wid & 1;        // wave = 32 rows x 64 cols
  int l15 = lane & 15, l4 = lane >> 4;
  int brow = blockIdx.x * 64;
  const int NKT = K >> 5;
  f32x4 acc[2][4] = {};

  float4 v[2];
  s16x8 bhc[4], blc[4], bhn[4], bln[4];
  s16x8 afh[2], afl[2];

  // --- prologue: load tile 0 (A + B), stage A, read frags ---
#pragma unroll
  for (int q = 0; q < 2; ++q) {
    int idx = tid + q * 256;
    int r = idx >> 3, c4 = (idx & 7) * 4;
    int gr = brow + r;
    v[q] = (gr < M) ? *(const float4*)&A[(size_t)gr * K + c4]
                    : make_float4(0.f, 0.f, 0.f, 0.f);
  }
#pragma unroll
  for (int n = 0; n < 4; ++n) {
    size_t o = (size_t)(wc * 64 + n * 16 + l15) * 32 + l4 * 8;
    bhc[n] = *(const s16x8*)&Bh[o];
    blc[n] = *(const s16x8*)&Bl[o];
  }
#pragma unroll
  for (int q = 0; q < 2; ++q) {
    int idx = tid + q * 256;
    int r = idx >> 3, c4 = (idx & 7) * 4;
    float4 w = v[q];
    unsigned short h0 = f2bf(w.x), h1 = f2bf(w.y), h2 = f2bf(w.z), h3 = f2bf(w.w);
    s16x4 hv = {(short)h0, (short)h1, (short)h2, (short)h3};
    s16x4 lv = {(short)f2bf(w.x - bf2f(h0)), (short)f2bf(w.y - bf2f(h1)),
                (short)f2bf(w.z - bf2f(h2)), (short)f2bf(w.w - bf2f(h3))};
    *(s16x4*)&Ah[r][c4] = hv;
    *(s16x4*)&Al[r][c4] = lv;
  }
  __syncthreads();
#pragma unroll
  for (int m = 0; m < 2; ++m) {
    int r = wr * 32 + m * 16 + l15;
    afh[m] = *(const s16x8*)&Ah[r][l4 * 8];
    afl[m] = *(const s16x8*)&Al[r][l4 * 8];
  }

  for (int kt = 0;; ++kt) {
    bool more = (kt + 1 < NKT);
    if (more) {
      // issue next tile's loads (A + B) -- consumed after the MFMAs below
      int k0 = (kt + 1) * 32;
#pragma unroll
      for (int q = 0; q < 2; ++q) {
        int idx = tid + q * 256;
        int r = idx >> 3, c4 = (idx & 7) * 4;
        int gr = brow + r;
        v[q] = (gr < M) ? *(const float4*)&A[(size_t)gr * K + k0 + c4]
                        : make_float4(0.f, 0.f, 0.f, 0.f);
      }
#pragma unroll
      for (int n = 0; n < 4; ++n) {
        size_t o = (size_t)(kt + 1) * 4096 + (size_t)(wc * 64 + n * 16 + l15) * 32 + l4 * 8;
        bhn[n] = *(const s16x8*)&Bh[o];
        bln[n] = *(const s16x8*)&Bl[o];
      }
    }
#pragma unroll
    for (int m = 0; m < 2; ++m)
#pragma unroll
      for (int n = 0; n < 4; ++n) {
        acc[m][n] = __builtin_amdgcn_mfma_f32_16x16x32_bf16(afh[m], bhc[n], acc[m][n], 0, 0, 0);
        acc[m][n] = __builtin_amdgcn_mfma_f32_16x16x32_bf16(afl[m], bhc[n], acc[m][n], 0, 0, 0);
        acc[m][n] = __builtin_amdgcn_mfma_f32_16x16x32_bf16(afh[m], blc[n], acc[m][n], 0, 0, 0);
      }
    if (!more) break;
    __syncthreads();  // all waves done reading Ah/Al of tile kt
#pragma unroll
    for (int q = 0; q < 2; ++q) {
      int idx = tid + q * 256;
      int r = idx >> 3, c4 = (idx & 7) * 4;
      float4 w = v[q];
      unsigned short h0 = f2bf(w.x), h1 = f2bf(w.y), h2 = f2bf(w.z), h3 = f2bf(w.w);
      s16x4 hv = {(short)h0, (short)h1, (short)h2, (short)h3};
      s16x4 lv = {(short)f2bf(w.x - bf2f(h0)), (short)f2bf(w.y - bf2f(h1)),
                  (short)f2bf(w.z - bf2f(h2)), (short)f2bf(w.w - bf2f(h3))};
      *(s16x4*)&Ah[r][c4] = hv;
      *(s16x4*)&Al[r][c4] = lv;
    }
    __syncthreads();
#pragma unroll
    for (int m = 0; m < 2; ++m) {
      int r = wr * 32 + m * 16 + l15;
      afh[m] = *(const s16x8*)&Ah[r][l4 * 8];
      afl[m] = *(const s16x8*)&Al[r][l4 * 8];
    }
#pragma unroll
    for (int n = 0; n < 4; ++n) { bhc[n] = bhn[n]; blc[n] = bln[n]; }
  }

#pragma unroll
  for (int m = 0; m < 2; ++m) {
    int rbase = brow + wr * 32 + m * 16 + l4 * 4;
#pragma unroll
    for (int n = 0; n < 4; ++n) {
      int c = wc * 64 + n * 16 + l15;
#pragma unroll
      for (int j = 0; j < 4; ++j) {
        int r = rbase + j;
        if (r < M) C[(size_t)r * 128 + c] = acc[m][n][j];
      }
    }
  }
}

// ---------------- gather-aggregate (CSR), float4-vectorized ----------------
// out[node] = (sum_j w_j * H[src_j] + dinv[node]*Hpre[node]) * dinv[node] + bias
// unweighted: w_j = dinv[src]; weighted: w_j = dinv[src]*ew_j

template <int F, bool RELU, bool WEIGHTED>
static __global__ __launch_bounds__(256) void k_gather4(
    const float* __restrict__ H, const int* __restrict__ rowptr,
    const int* __restrict__ src, const int2* __restrict__ srcw,
    const float* __restrict__ dinv, const float* __restrict__ Hpre,
    const float* __restrict__ bias, float* __restrict__ out, int n) {
  const int L = F / 4;
  int node = blockIdx.x * (256 / L) + threadIdx.x / L;
  if (node >= n) return;
  int f4 = (threadIdx.x % L) * 4;
  float d = dinv[node];
  float4 hp = *(const float4*)&Hpre[(size_t)node * F + f4];
  float ax = hp.x * d, ay = hp.y * d, az = hp.z * d, aw = hp.w * d;
  int j = rowptr[node], e = rowptr[node + 1];
  for (; j + 1 < e; j += 2) {
    int r0, r1;
    float w0, w1;
    if (WEIGHTED) {
      int2 a = srcw[j], b = srcw[j + 1];
      r0 = a.x; r1 = b.x;
      w0 = dinv[r0] * __int_as_float(a.y);
      w1 = dinv[r1] * __int_as_float(b.y);
    } else {
      r0 = src[j]; r1 = src[j + 1];
      w0 = dinv[r0]; w1 = dinv[r1];
    }
    float4 v0 = *(const float4*)&H[(size_t)r0 * F + f4];
    float4 v1 = *(const float4*)&H[(size_t)r1 * F + f4];
    ax += v0.x * w0 + v1.x * w1;
    ay += v0.y * w0 + v1.y * w1;
    az += v0.z * w0 + v1.z * w1;
    aw += v0.w * w0 + v1.w * w1;
  }
  if (j < e) {
    int r;
    float wj;
    if (WEIGHTED) { int2 a = srcw[j]; r = a.x; wj = dinv[r] * __int_as_float(a.y); }
    else { r = src[j]; wj = dinv[r]; }
    float4 v = *(const float4*)&H[(size_t)r * F + f4];
    ax += v.x * wj; ay += v.y * wj; az += v.z * wj; aw += v.w * wj;
  }
  float bx = 0, by = 0, bz = 0, bw = 0;
  if (bias) { float4 bb = *(const float4*)&bias[f4]; bx = bb.x; by = bb.y; bz = bb.z; bw = bb.w; }
  ax = ax * d + bx; ay = ay * d + by; az = az * d + bz; aw = aw * d + bw;
  if (RELU) { ax = fmaxf(ax, 0.f); ay = fmaxf(ay, 0.f); az = fmaxf(az, 0.f); aw = fmaxf(aw, 0.f); }
  float4 o; o.x = ax; o.y = ay; o.z = az; o.w = aw;
  *(float4*)&out[(size_t)node * F + f4] = o;
}

// ---------------- fp32 tiled GEMM (small N: conv2 + heads) ----------------

static __global__ __launch_bounds__(256) void k_gemm(
    const float* __restrict__ A, const float* __restrict__ B,
    const float* __restrict__ bias, float* __restrict__ C,
    int M, int N, int K) {
  const int BM = 64, BN = 64, BK = 16;
  __shared__ float As[BK][BM + 4];
  __shared__ float Bs[BK][BN + 4];
  int tid = threadIdx.x;
  int tr = tid >> 4, tc = tid & 15;
  int brow = blockIdx.y * BM, bcol = blockIdx.x * BN;
  float acc[4][4] = {};
  for (int k0 = 0; k0 < K; k0 += BK) {
#pragma unroll
    for (int i = tid; i < BM * BK; i += 256) {
      int m = i >> 4, kk = i & 15;
      int gr = brow + m;
      As[kk][m] = (gr < M) ? A[(size_t)gr * K + k0 + kk] : 0.f;
    }
#pragma unroll
    for (int i = tid; i < BK * BN; i += 256) {
      int kk = i >> 6, n = i & 63;
      int gc = bcol + n;
      Bs[kk][n] = (gc < N) ? B[(size_t)(k0 + kk) * N + gc] : 0.f;
    }
    __syncthreads();
#pragma unroll
    for (int kk = 0; kk < BK; ++kk) {
      float a[4], b[4];
#pragma unroll
      for (int i = 0; i < 4; ++i) a[i] = As[kk][tr * 4 + i];
#pragma unroll
      for (int j = 0; j < 4; ++j) b[j] = Bs[kk][tc * 4 + j];
#pragma unroll
      for (int i = 0; i < 4; ++i)
#pragma unroll
        for (int j = 0; j < 4; ++j) acc[i][j] += a[i] * b[j];
    }
    __syncthreads();
  }
#pragma unroll
  for (int i = 0; i < 4; ++i) {
    int r = brow + tr * 4 + i;
    if (r >= M) continue;
#pragma unroll
    for (int j = 0; j < 4; ++j) {
      int c = bcol + tc * 4 + j;
      if (c < N) C[(size_t)r * N + c] = acc[i][j] + (bias ? bias[c] : 0.f);
    }
  }
}

// ---------------- log-softmax over 40 classes, in place ----------------

static __global__ void k_logsoftmax40(float* __restrict__ X, int n) {
  int i = blockIdx.x * blockDim.x + threadIdx.x;
  if (i >= n) return;
  float4 v[10];
#pragma unroll
  for (int q = 0; q < 10; ++q) v[q] = *(const float4*)&X[(size_t)i * 40 + q * 4];
  float m = -1e30f;
#pragma unroll
  for (int q = 0; q < 10; ++q)
    m = fmaxf(m, fmaxf(fmaxf(v[q].x, v[q].y), fmaxf(v[q].z, v[q].w)));
  float s = 0.f;
#pragma unroll
  for (int q = 0; q < 10; ++q)
    s += expf(v[q].x - m) + expf(v[q].y - m) + expf(v[q].z - m) + expf(v[q].w - m);
  float ls = logf(s) + m;
#pragma unroll
  for (int q = 0; q < 10; ++q) {
    float4 o; o.x = v[q].x - ls; o.y = v[q].y - ls; o.z = v[q].z - ls; o.w = v[q].w - ls;
    *(float4*)&X[(size_t)i * 40 + q * 4] = o;
  }
}

// ---------------- link prediction ----------------

static __global__ __launch_bounds__(256) void k_linkpred4(
    const float* __restrict__ H2, const int* __restrict__ pos,
    const int* __restrict__ neg, float* __restrict__ res, int Elp) {
  int t = blockIdx.x * 256 + threadIdx.x;
  int e = t >> 4, f4 = (t & 15) * 4;
  if (e >= 2 * Elp) return;
  int a, b;
  if (e < Elp) { a = pos[e]; b = pos[Elp + e]; }
  else { int e2 = e - Elp; a = neg[e2]; b = neg[Elp + e2]; }
  float4 va = *(const float4*)&H2[(size_t)a * 64 + f4];
  float4 vb = *(const float4*)&H2[(size_t)b * 64 + f4];
  float p = va.x * vb.x + va.y * vb.y + va.z * vb.z + va.w * vb.w;
  p += __shfl_xor(p, 1);
  p += __shfl_xor(p, 2);
  p += __shfl_xor(p, 4);
  p += __shfl_xor(p, 8);
  if ((t & 15) == 0) res[e] = p;
}

// ---------------- launch ----------------

extern "C" void kernel_launch(void* const* d_in, const int* in_sizes, int n_in,
                              void* d_out, int out_size, void* d_ws, size_t ws_size,
                              hipStream_t stream) {
  const float* x    = (const float*)d_in[0];
  const int*   tp   = (const int*)d_in[1];
  const int*   ei   = (const int*)d_in[2];
  const float* ew   = (const float*)d_in[3];
  const int*   pos  = (const int*)d_in[4];
  const int*   neg  = (const int*)d_in[5];
  const float* W1   = (const float*)d_in[6];
  const float* b1   = (const float*)d_in[7];
  const float* W2   = (const float*)d_in[8];
  const float* b2   = (const float*)d_in[9];
  const float* Wattr= (const float*)d_in[10];
  const float* battr= (const float*)d_in[11];
  const float* Watt = (const float*)d_in[12];
  const float* batt = (const float*)d_in[13];

  const int N   = in_sizes[0] / 512;  // 50000
  const int EMP = in_sizes[1] / 2;    // 800000
  const int ELP = in_sizes[4] / 2;    // 250000
  const int NB  = (N + 1023) / 1024;  // scan blocks per array

  // workspace layout (4B units, 16B-aligned regions)
  float* ws = (float*)d_ws;
  float* dinvT = ws;                          // N
  float* dinvE = dinvT + N;                   // N
  int* rowptrT = (int*)(dinvE + N);           // N+1 (+pad)
  int* rowptrE = rowptrT + (N + 4);           // N+1 (+pad)
  int* srcT    = rowptrE + (N + 4);           // EMP
  int2* srcwE  = (int2*)(srcT + EMP);         // EMP int2
  int* bsum    = (int*)(srcwE + EMP);         // 2*NB (+pad)
  unsigned short* W1h = (unsigned short*)(bsum + 128);  // 512*128 bf16 (k-tiled)
  unsigned short* W1l = W1h + 512 * 128;                // 512*128 bf16 (k-tiled)
  float* bufA  = (float*)(W1l + 512 * 128);   // N*128
  float* bufB  = bufA + (size_t)N * 128;      // N*128
  float* bufC  = bufB + (size_t)N * 128;      // N*64
  // overlays (dead before their hosts are written):
  int* rankT = (int*)bufA;                    // EMP (dead after k_fill; bufA written later)
  int* rankE = rankT + EMP;                   // EMP
  int* cntT  = (int*)bufB;                    // N (dead after k_dinv2; bufB written later)
  int* cntE  = cntT + N;                      // N

  float* out_res  = (float*)d_out;
  float* out_attr = out_res + 2 * (size_t)ELP;
  float* out_att  = out_attr + (size_t)N * 40;

  dim3 b256(256);
  int gN = (N + 255) / 256;
  int gE = (EMP + 255) / 256;

  // CSR build + norms (+ W1 convert, independent)
  k_init<<<gN, b256, 0, stream>>>(cntT, cntE, N);
  k_cvtW<<<(512 * 128 + 255) / 256, b256, 0, stream>>>(W1, W1h, W1l, 512, 128);
  k_count<<<gE, b256, 0, stream>>>(tp + EMP, ei + EMP, cntT, cntE, rankT, rankE, EMP);
  {
    dim3 gs(NB, 2);
    k_scanA<<<gs, b256, 0, stream>>>(cntT, cntE, bsum, N, NB);
    k_scanB<<<1, 64, 0, stream>>>(bsum, rowptrT, rowptrE, NB, N);
    k_scanC<<<gs, b256, 0, stream>>>(cntT, cntE, bsum, rowptrT, rowptrE, N, NB);
  }
  k_fill<<<gE, b256, 0, stream>>>(tp, tp + EMP, ei, ei + EMP, ew,
                                  rowptrT, rowptrE, rankT, rankE, srcT, srcwE, EMP);
  k_dinv2<<<gN, b256, 0, stream>>>(cntT, srcwE, rowptrE, dinvT, dinvE, N);

  // conv1: h1_pre = x @ W1 (MFMA split-bf16) ; h = relu(Agg_T(h1_pre) + b1)
  k_gemm_mfma_split<<<(N + 63) / 64, b256, 0, stream>>>(x, W1h, W1l, bufA, N, 512);
  k_gather4<128, true, false><<<(N + 7) / 8, b256, 0, stream>>>(
      bufA, rowptrT, srcT, nullptr, dinvT, bufA, b1, bufB, N);

  // conv2: h2_pre = h @ W2 ; h2 = Agg_T(h2_pre) + b2
  {
    dim3 grid(1, (N + 63) / 64);
    k_gemm<<<grid, b256, 0, stream>>>(bufB, W2, nullptr, bufA, N, 64, 128);
  }
  k_gather4<64, false, false><<<(N + 15) / 16, b256, 0, stream>>>(
      bufA, rowptrT, srcT, nullptr, dinvT, bufA, b2, bufC, N);

  // conv3/4 share aggregation: agg3 = Agg_E(h2) into bufA
  k_gather4<64, false, true><<<(N + 15) / 16, b256, 0, stream>>>(
      bufC, rowptrE, nullptr, srcwE, dinvE, bufC, nullptr, bufA, N);

  // heads
  {
    dim3 grid(1, (N + 63) / 64);
    k_gemm<<<grid, b256, 0, stream>>>(bufA, Wattr, battr, out_attr, N, 40, 64);
    k_gemm<<<grid, b256, 0, stream>>>(bufA, Watt, batt, out_att, N, 40, 64);
  }
  k_logsoftmax40<<<gN, b256, 0, stream>>>(out_attr, N);
  k_logsoftmax40<<<gN, b256, 0, stream>>>(out_att, N);

  // link prediction (h2 = bufC)
  k_linkpred4<<<(2 * ELP * 16 + 255) / 256, b256, 0, stream>>>(bufC, pos, neg, out_res, ELP);
}

// Round 7
// 430.370 us; speedup vs baseline: 1.0585x; 1.0109x over previous
//
#include <hip/hip_runtime.h>

typedef short s16x8 __attribute__((ext_vector_type(8)));
typedef short s16x4 __attribute__((ext_vector_type(4)));
typedef float f32x4 __attribute__((ext_vector_type(4)));

static __device__ __forceinline__ unsigned short f2bf(float f) {
  unsigned u = __float_as_uint(f);
  u += 0x7fff + ((u >> 16) & 1);  // round-to-nearest-even
  return (unsigned short)(u >> 16);
}
static __device__ __forceinline__ float bf2f(unsigned short h) {
  return __uint_as_float(((unsigned)h) << 16);
}

// ---------------- CSR build ----------------

static __global__ void k_init(int* cntT, int* cntE, int n) {
  int i = blockIdx.x * blockDim.x + threadIdx.x;
  if (i < n) { cntT[i] = 0; cntE[i] = 0; }
}

// counts + per-edge rank; 4 edges/thread for memory-level parallelism
static __global__ void k_count(const int* __restrict__ tcol, const int* __restrict__ ecol,
                               int* __restrict__ cntT, int* __restrict__ cntE,
                               int* __restrict__ rankT, int* __restrict__ rankE, int E) {
  int base = (blockIdx.x * blockDim.x + threadIdx.x) * 4;
  if (base + 3 < E) {
    int4 tc = *(const int4*)&tcol[base];
    int4 ec = *(const int4*)&ecol[base];
    int4 rt, re;
    rt.x = atomicAdd(&cntT[tc.x], 1);
    rt.y = atomicAdd(&cntT[tc.y], 1);
    rt.z = atomicAdd(&cntT[tc.z], 1);
    rt.w = atomicAdd(&cntT[tc.w], 1);
    re.x = atomicAdd(&cntE[ec.x], 1);
    re.y = atomicAdd(&cntE[ec.y], 1);
    re.z = atomicAdd(&cntE[ec.z], 1);
    re.w = atomicAdd(&cntE[ec.w], 1);
    *(int4*)&rankT[base] = rt;
    *(int4*)&rankE[base] = re;
  } else {
    for (int e = base; e < E; ++e) {
      rankT[e] = atomicAdd(&cntT[tcol[e]], 1);
      rankE[e] = atomicAdd(&cntE[ecol[e]], 1);
    }
  }
}

// 3-phase exclusive scan over both count arrays (grid.y selects array)
static __global__ __launch_bounds__(256) void k_scanA(
    const int* __restrict__ cntT, const int* __restrict__ cntE,
    int* __restrict__ bsum, int n, int nb) {
  const int* cnt = blockIdx.y ? cntE : cntT;
  int tid = threadIdx.x;
  int base = blockIdx.x * 1024 + tid * 4;
  int s = 0;
#pragma unroll
  for (int q = 0; q < 4; ++q) { int i = base + q; if (i < n) s += cnt[i]; }
  __shared__ int red[256];
  red[tid] = s;
  __syncthreads();
  for (int off = 128; off > 0; off >>= 1) {
    if (tid < off) red[tid] += red[tid + off];
    __syncthreads();
  }
  if (tid == 0) bsum[blockIdx.y * nb + blockIdx.x] = red[0];
}

static __global__ void k_scanB(int* bsum, int* ptrT, int* ptrE, int nb, int n) {
  int a = threadIdx.x;
  if (a > 1) return;
  int* bs = bsum + a * nb;
  int run = 0;
  for (int i = 0; i < nb; ++i) { int c = bs[i]; bs[i] = run; run += c; }
  (a ? ptrE : ptrT)[n] = run;
}

static __global__ __launch_bounds__(256) void k_scanC(
    const int* __restrict__ cntT, const int* __restrict__ cntE,
    const int* __restrict__ bsum, int* __restrict__ ptrT, int* __restrict__ ptrE,
    int n, int nb) {
  const int* cnt = blockIdx.y ? cntE : cntT;
  int* ptr = blockIdx.y ? ptrE : ptrT;
  int tid = threadIdx.x;
  int pre = bsum[blockIdx.y * nb + blockIdx.x];
  int base = blockIdx.x * 1024 + tid * 4;
  int v[4];
  int s = 0;
#pragma unroll
  for (int q = 0; q < 4; ++q) { int i = base + q; v[q] = (i < n) ? cnt[i] : 0; s += v[q]; }
  __shared__ int red[256];
  red[tid] = s;
  __syncthreads();
  for (int off = 1; off < 256; off <<= 1) {
    int t = (tid >= off) ? red[tid - off] : 0;
    __syncthreads();
    red[tid] += t;
    __syncthreads();
  }
  int run = pre + (tid ? red[tid - 1] : 0);
#pragma unroll
  for (int q = 0; q < 4; ++q) {
    int i = base + q;
    if (i < n) ptr[i] = run;
    run += v[q];
  }
}

// atomic-free fill: slot = ptr[col] + rank; 4 edges/thread
static __global__ void k_fill(const int* __restrict__ trow, const int* __restrict__ tcol,
                              const int* __restrict__ erow, const int* __restrict__ ecol,
                              const float* __restrict__ ew,
                              const int* __restrict__ ptrT, const int* __restrict__ ptrE,
                              const int* __restrict__ rankT, const int* __restrict__ rankE,
                              int* __restrict__ srcT, int2* __restrict__ srcwE, int E) {
  int base = (blockIdx.x * blockDim.x + threadIdx.x) * 4;
  if (base + 3 < E) {
    int4 tr = *(const int4*)&trow[base];
    int4 tc = *(const int4*)&tcol[base];
    int4 er = *(const int4*)&erow[base];
    int4 ec = *(const int4*)&ecol[base];
    float4 w = *(const float4*)&ew[base];
    int4 rt = *(const int4*)&rankT[base];
    int4 re = *(const int4*)&rankE[base];
    srcT[ptrT[tc.x] + rt.x] = tr.x;
    srcT[ptrT[tc.y] + rt.y] = tr.y;
    srcT[ptrT[tc.z] + rt.z] = tr.z;
    srcT[ptrT[tc.w] + rt.w] = tr.w;
    int2 p;
    p.x = er.x; p.y = __float_as_int(w.x); srcwE[ptrE[ec.x] + re.x] = p;
    p.x = er.y; p.y = __float_as_int(w.y); srcwE[ptrE[ec.y] + re.y] = p;
    p.x = er.z; p.y = __float_as_int(w.z); srcwE[ptrE[ec.z] + re.z] = p;
    p.x = er.w; p.y = __float_as_int(w.w); srcwE[ptrE[ec.w] + re.w] = p;
  } else {
    for (int e = base; e < E; ++e) {
      srcT[ptrT[tcol[e]] + rankT[e]] = trow[e];
      int2 p;
      p.x = erow[e];
      p.y = __float_as_int(ew[e]);
      srcwE[ptrE[ecol[e]] + rankE[e]] = p;
    }
  }
}

// dinvT from counts; dinvE from CSR segment-sum of ew
static __global__ void k_dinv2(const int* __restrict__ cntT, const int2* __restrict__ srcwE,
                               const int* __restrict__ ptrE,
                               float* __restrict__ dinvT, float* __restrict__ dinvE, int n) {
  int i = blockIdx.x * blockDim.x + threadIdx.x;
  if (i >= n) return;
  dinvT[i] = rsqrtf((float)cntT[i] + 1.0f);
  float s = 1.0f;  // self loop
  int e = ptrE[i + 1];
  for (int j = ptrE[i]; j < e; ++j) s += __int_as_float(srcwE[j].y);
  dinvE[i] = rsqrtf(s);
}

// ---------------- W1 -> k-tiled transposed bf16 split ----------------
// Output layout: Wh/Wl[kt][c][kk]  (kt = k/32, kk = k%32, c = 0..127)

static __global__ void k_cvtW(const float* __restrict__ W, unsigned short* __restrict__ Wh,
                              unsigned short* __restrict__ Wl, int K, int Nc) {
  int t = blockIdx.x * blockDim.x + threadIdx.x;
  if (t >= K * Nc) return;
  int k = t / Nc, c = t - k * Nc;
  float v = W[t];
  unsigned short hi = f2bf(v);
  size_t o = (size_t)(k >> 5) * (Nc * 32) + c * 32 + (k & 31);
  Wh[o] = hi;
  Wl[o] = f2bf(v - bf2f(hi));
}

// ---------------- MFMA split-bf16 GEMM: C[M][128] = A[M][512] @ B[512][128] ----------------
// 64-row tiles, K=512 hard-coded (full unroll). A: 2-stage LDS double buffer,
// global load issued one full k-step before its convert+store. B: cur/next
// register pairs from L2-resident k-tiled layout. One barrier per k-step.

#define PADU 36   // LDS row stride in ushort (72 B)
#define GK 512
#define NKT 16

static __global__ __launch_bounds__(256) void k_gemm_mfma_split(
    const float* __restrict__ A, const unsigned short* __restrict__ Bh,
    const unsigned short* __restrict__ Bl, float* __restrict__ C, int M) {
  __shared__ __align__(16) unsigned short Ah[2][64][PADU];
  __shared__ __align__(16) unsigned short Al[2][64][PADU];
  int tid = threadIdx.x;
  int lane = tid & 63, wid = tid >> 6;
  int wr = wid >> 1, wc = wid & 1;        // wave = 32 rows x 64 cols
  int l15 = lane & 15, l4 = lane >> 4;
  int brow = blockIdx.x * 64;
  f32x4 acc[2][4] = {};

  // per-thread A-load coords: 8 threads per row, float4 each
  int ar = tid >> 3, ac4 = (tid & 7) * 4;
  int ar2 = (tid + 256) >> 3, ac42 = ((tid + 256) & 7) * 4;
  const float* Arow1 = &A[(size_t)min(brow + ar, M - 1) * GK + ac4];
  const float* Arow2 = &A[(size_t)min(brow + ar2, M - 1) * GK + ac42];
  bool v1ok = (brow + ar < M), v2ok = (brow + ar2 < M);

  float4 v[2];
  s16x8 bhc[4], blc[4], bhn[4], bln[4];
  size_t boff = (size_t)(wc * 64 + l15) * 32 + l4 * 8;  // + n*16*32 + kt*4096

  // ---- prologue ----
  v[0] = v1ok ? *(const float4*)Arow1 : make_float4(0.f, 0.f, 0.f, 0.f);
  v[1] = v2ok ? *(const float4*)Arow2 : make_float4(0.f, 0.f, 0.f, 0.f);
#pragma unroll
  for (int n = 0; n < 4; ++n) {
    bhc[n] = *(const s16x8*)&Bh[boff + n * 512];
    blc[n] = *(const s16x8*)&Bl[boff + n * 512];
  }
  // convert tile 0 into LDS[0]
  {
    float4 w0 = v[0], w1 = v[1];
    unsigned short h;
    s16x4 hv, lv;
    h = f2bf(w0.x); hv[0] = h; lv[0] = (short)f2bf(w0.x - bf2f(h));
    h = f2bf(w0.y); hv[1] = h; lv[1] = (short)f2bf(w0.y - bf2f(h));
    h = f2bf(w0.z); hv[2] = h; lv[2] = (short)f2bf(w0.z - bf2f(h));
    h = f2bf(w0.w); hv[3] = h; lv[3] = (short)f2bf(w0.w - bf2f(h));
    *(s16x4*)&Ah[0][ar][ac4] = hv;
    *(s16x4*)&Al[0][ar][ac4] = lv;
    h = f2bf(w1.x); hv[0] = h; lv[0] = (short)f2bf(w1.x - bf2f(h));
    h = f2bf(w1.y); hv[1] = h; lv[1] = (short)f2bf(w1.y - bf2f(h));
    h = f2bf(w1.z); hv[2] = h; lv[2] = (short)f2bf(w1.z - bf2f(h));
    h = f2bf(w1.w); hv[3] = h; lv[3] = (short)f2bf(w1.w - bf2f(h));
    *(s16x4*)&Ah[0][ar2][ac42] = hv;
    *(s16x4*)&Al[0][ar2][ac42] = lv;
  }
  // load A(1), B(1)
  v[0] = v1ok ? *(const float4*)(Arow1 + 32) : make_float4(0.f, 0.f, 0.f, 0.f);
  v[1] = v2ok ? *(const float4*)(Arow2 + 32) : make_float4(0.f, 0.f, 0.f, 0.f);
#pragma unroll
  for (int n = 0; n < 4; ++n) {
    bhn[n] = *(const s16x8*)&Bh[4096 + boff + n * 512];
    bln[n] = *(const s16x8*)&Bl[4096 + boff + n * 512];
  }
  __syncthreads();

  // ---- main loop ----
#pragma unroll
  for (int kt = 0; kt < NKT; ++kt) {
    int S = kt & 1;
    s16x8 afh[2], afl[2];
#pragma unroll
    for (int m = 0; m < 2; ++m) {
      int r = wr * 32 + m * 16 + l15;
      afh[m] = *(const s16x8*)&Ah[S][r][l4 * 8];
      afl[m] = *(const s16x8*)&Al[S][r][l4 * 8];
    }
    if (kt + 1 < NKT) {
      // convert tile kt+1 (in v) into LDS[S^1]
      float4 w0 = v[0], w1 = v[1];
      unsigned short h;
      s16x4 hv, lv;
      h = f2bf(w0.x); hv[0] = h; lv[0] = (short)f2bf(w0.x - bf2f(h));
      h = f2bf(w0.y); hv[1] = h; lv[1] = (short)f2bf(w0.y - bf2f(h));
      h = f2bf(w0.z); hv[2] = h; lv[2] = (short)f2bf(w0.z - bf2f(h));
      h = f2bf(w0.w); hv[3] = h; lv[3] = (short)f2bf(w0.w - bf2f(h));
      *(s16x4*)&Ah[S ^ 1][ar][ac4] = hv;
      *(s16x4*)&Al[S ^ 1][ar][ac4] = lv;
      h = f2bf(w1.x); hv[0] = h; lv[0] = (short)f2bf(w1.x - bf2f(h));
      h = f2bf(w1.y); hv[1] = h; lv[1] = (short)f2bf(w1.y - bf2f(h));
      h = f2bf(w1.z); hv[2] = h; lv[2] = (short)f2bf(w1.z - bf2f(h));
      h = f2bf(w1.w); hv[3] = h; lv[3] = (short)f2bf(w1.w - bf2f(h));
      *(s16x4*)&Ah[S ^ 1][ar2][ac42] = hv;
      *(s16x4*)&Al[S ^ 1][ar2][ac42] = lv;
      if (kt + 2 < NKT) {
        // issue A loads for kt+2 (consumed next iteration)
        v[0] = v1ok ? *(const float4*)(Arow1 + (kt + 2) * 32) : make_float4(0.f, 0.f, 0.f, 0.f);
        v[1] = v2ok ? *(const float4*)(Arow2 + (kt + 2) * 32) : make_float4(0.f, 0.f, 0.f, 0.f);
      }
    }
#pragma unroll
    for (int m = 0; m < 2; ++m)
#pragma unroll
      for (int n = 0; n < 4; ++n) {
        acc[m][n] = __builtin_amdgcn_mfma_f32_16x16x32_bf16(afh[m], bhc[n], acc[m][n], 0, 0, 0);
        acc[m][n] = __builtin_amdgcn_mfma_f32_16x16x32_bf16(afl[m], bhc[n], acc[m][n], 0, 0, 0);
        acc[m][n] = __builtin_amdgcn_mfma_f32_16x16x32_bf16(afh[m], blc[n], acc[m][n], 0, 0, 0);
      }
    if (kt + 1 < NKT) {
#pragma unroll
      for (int n = 0; n < 4; ++n) { bhc[n] = bhn[n]; blc[n] = bln[n]; }
      if (kt + 2 < NKT) {
        size_t o = (size_t)(kt + 2) * 4096 + boff;
#pragma unroll
        for (int n = 0; n < 4; ++n) {
          bhn[n] = *(const s16x8*)&Bh[o + n * 512];
          bln[n] = *(const s16x8*)&Bl[o + n * 512];
        }
      }
      __syncthreads();
    }
  }

#pragma unroll
  for (int m = 0; m < 2; ++m) {
    int rbase = brow + wr * 32 + m * 16 + l4 * 4;
#pragma unroll
    for (int n = 0; n < 4; ++n) {
      int c = wc * 64 + n * 16 + l15;
#pragma unroll
      for (int j = 0; j < 4; ++j) {
        int r = rbase + j;
        if (r < M) C[(size_t)r * 128 + c] = acc[m][n][j];
      }
    }
  }
}

// ---------------- gather-aggregate (CSR), float4-vectorized ----------------

template <int F, bool RELU, bool WEIGHTED>
static __global__ __launch_bounds__(256) void k_gather4(
    const float* __restrict__ H, const int* __restrict__ rowptr,
    const int* __restrict__ src, const int2* __restrict__ srcw,
    const float* __restrict__ dinv, const float* __restrict__ Hpre,
    const float* __restrict__ bias, float* __restrict__ out, int n) {
  const int L = F / 4;
  int node = blockIdx.x * (256 / L) + threadIdx.x / L;
  if (node >= n) return;
  int f4 = (threadIdx.x % L) * 4;
  float d = dinv[node];
  float4 hp = *(const float4*)&Hpre[(size_t)node * F + f4];
  float ax = hp.x * d, ay = hp.y * d, az = hp.z * d, aw = hp.w * d;
  int j = rowptr[node], e = rowptr[node + 1];
  for (; j + 1 < e; j += 2) {
    int r0, r1;
    float w0, w1;
    if (WEIGHTED) {
      int2 a = srcw[j], b = srcw[j + 1];
      r0 = a.x; r1 = b.x;
      w0 = dinv[r0] * __int_as_float(a.y);
      w1 = dinv[r1] * __int_as_float(b.y);
    } else {
      r0 = src[j]; r1 = src[j + 1];
      w0 = dinv[r0]; w1 = dinv[r1];
    }
    float4 v0 = *(const float4*)&H[(size_t)r0 * F + f4];
    float4 v1 = *(const float4*)&H[(size_t)r1 * F + f4];
    ax += v0.x * w0 + v1.x * w1;
    ay += v0.y * w0 + v1.y * w1;
    az += v0.z * w0 + v1.z * w1;
    aw += v0.w * w0 + v1.w * w1;
  }
  if (j < e) {
    int r;
    float wj;
    if (WEIGHTED) { int2 a = srcw[j]; r = a.x; wj = dinv[r] * __int_as_float(a.y); }
    else { r = src[j]; wj = dinv[r]; }
    float4 v = *(const float4*)&H[(size_t)r * F + f4];
    ax += v.x * wj; ay += v.y * wj; az += v.z * wj; aw += v.w * wj;
  }
  float bx = 0, by = 0, bz = 0, bw = 0;
  if (bias) { float4 bb = *(const float4*)&bias[f4]; bx = bb.x; by = bb.y; bz = bb.z; bw = bb.w; }
  ax = ax * d + bx; ay = ay * d + by; az = az * d + bz; aw = aw * d + bw;
  if (RELU) { ax = fmaxf(ax, 0.f); ay = fmaxf(ay, 0.f); az = fmaxf(az, 0.f); aw = fmaxf(aw, 0.f); }
  float4 o; o.x = ax; o.y = ay; o.z = az; o.w = aw;
  *(float4*)&out[(size_t)node * F + f4] = o;
}

// ---------------- fp32 tiled GEMM (small N: conv2 + heads) ----------------

static __global__ __launch_bounds__(256) void k_gemm(
    const float* __restrict__ A, const float* __restrict__ B,
    const float* __restrict__ bias, float* __restrict__ C,
    int M, int N, int K) {
  const int BM = 64, BN = 64, BK = 16;
  __shared__ float As[BK][BM + 4];
  __shared__ float Bs[BK][BN + 4];
  int tid = threadIdx.x;
  int tr = tid >> 4, tc = tid & 15;
  int brow = blockIdx.y * BM, bcol = blockIdx.x * BN;
  float acc[4][4] = {};
  for (int k0 = 0; k0 < K; k0 += BK) {
#pragma unroll
    for (int i = tid; i < BM * BK; i += 256) {
      int m = i >> 4, kk = i & 15;
      int gr = brow + m;
      As[kk][m] = (gr < M) ? A[(size_t)gr * K + k0 + kk] : 0.f;
    }
#pragma unroll
    for (int i = tid; i < BK * BN; i += 256) {
      int kk = i >> 6, n = i & 63;
      int gc = bcol + n;
      Bs[kk][n] = (gc < N) ? B[(size_t)(k0 + kk) * N + gc] : 0.f;
    }
    __syncthreads();
#pragma unroll
    for (int kk = 0; kk < BK; ++kk) {
      float a[4], b[4];
#pragma unroll
      for (int i = 0; i < 4; ++i) a[i] = As[kk][tr * 4 + i];
#pragma unroll
      for (int j = 0; j < 4; ++j) b[j] = Bs[kk][tc * 4 + j];
#pragma unroll
      for (int i = 0; i < 4; ++i)
#pragma unroll
        for (int j = 0; j < 4; ++j) acc[i][j] += a[i] * b[j];
    }
    __syncthreads();
  }
#pragma unroll
  for (int i = 0; i < 4; ++i) {
    int r = brow + tr * 4 + i;
    if (r >= M) continue;
#pragma unroll
    for (int j = 0; j < 4; ++j) {
      int c = bcol + tc * 4 + j;
      if (c < N) C[(size_t)r * N + c] = acc[i][j] + (bias ? bias[c] : 0.f);
    }
  }
}

// ---------------- log-softmax over 40 classes, in place ----------------

static __global__ void k_logsoftmax40(float* __restrict__ X, int n) {
  int i = blockIdx.x * blockDim.x + threadIdx.x;
  if (i >= n) return;
  float4 v[10];
#pragma unroll
  for (int q = 0; q < 10; ++q) v[q] = *(const float4*)&X[(size_t)i * 40 + q * 4];
  float m = -1e30f;
#pragma unroll
  for (int q = 0; q < 10; ++q)
    m = fmaxf(m, fmaxf(fmaxf(v[q].x, v[q].y), fmaxf(v[q].z, v[q].w)));
  float s = 0.f;
#pragma unroll
  for (int q = 0; q < 10; ++q)
    s += expf(v[q].x - m) + expf(v[q].y - m) + expf(v[q].z - m) + expf(v[q].w - m);
  float ls = logf(s) + m;
#pragma unroll
  for (int q = 0; q < 10; ++q) {
    float4 o; o.x = v[q].x - ls; o.y = v[q].y - ls; o.z = v[q].z - ls; o.w = v[q].w - ls;
    *(float4*)&X[(size_t)i * 40 + q * 4] = o;
  }
}

// ---------------- link prediction ----------------

static __global__ __launch_bounds__(256) void k_linkpred4(
    const float* __restrict__ H2, const int* __restrict__ pos,
    const int* __restrict__ neg, float* __restrict__ res, int Elp) {
  int t = blockIdx.x * 256 + threadIdx.x;
  int e = t >> 4, f4 = (t & 15) * 4;
  if (e >= 2 * Elp) return;
  int a, b;
  if (e < Elp) { a = pos[e]; b = pos[Elp + e]; }
  else { int e2 = e - Elp; a = neg[e2]; b = neg[Elp + e2]; }
  float4 va = *(const float4*)&H2[(size_t)a * 64 + f4];
  float4 vb = *(const float4*)&H2[(size_t)b * 64 + f4];
  float p = va.x * vb.x + va.y * vb.y + va.z * vb.z + va.w * vb.w;
  p += __shfl_xor(p, 1);
  p += __shfl_xor(p, 2);
  p += __shfl_xor(p, 4);
  p += __shfl_xor(p, 8);
  if ((t & 15) == 0) res[e] = p;
}

// ---------------- launch ----------------

extern "C" void kernel_launch(void* const* d_in, const int* in_sizes, int n_in,
                              void* d_out, int out_size, void* d_ws, size_t ws_size,
                              hipStream_t stream) {
  const float* x    = (const float*)d_in[0];
  const int*   tp   = (const int*)d_in[1];
  const int*   ei   = (const int*)d_in[2];
  const float* ew   = (const float*)d_in[3];
  const int*   pos  = (const int*)d_in[4];
  const int*   neg  = (const int*)d_in[5];
  const float* W1   = (const float*)d_in[6];
  const float* b1   = (const float*)d_in[7];
  const float* W2   = (const float*)d_in[8];
  const float* b2   = (const float*)d_in[9];
  const float* Wattr= (const float*)d_in[10];
  const float* battr= (const float*)d_in[11];
  const float* Watt = (const float*)d_in[12];
  const float* batt = (const float*)d_in[13];

  const int N   = in_sizes[0] / 512;  // 50000
  const int EMP = in_sizes[1] / 2;    // 800000
  const int ELP = in_sizes[4] / 2;    // 250000
  const int NB  = (N + 1023) / 1024;  // scan blocks per array

  // workspace layout (4B units, 16B-aligned regions)
  float* ws = (float*)d_ws;
  float* dinvT = ws;                          // N
  float* dinvE = dinvT + N;                   // N
  int* rowptrT = (int*)(dinvE + N);           // N+1 (+pad)
  int* rowptrE = rowptrT + (N + 4);           // N+1 (+pad)
  int* srcT    = rowptrE + (N + 4);           // EMP
  int2* srcwE  = (int2*)(srcT + EMP);         // EMP int2
  int* bsum    = (int*)(srcwE + EMP);         // 2*NB (+pad)
  unsigned short* W1h = (unsigned short*)(bsum + 128);  // 512*128 bf16 (k-tiled)
  unsigned short* W1l = W1h + 512 * 128;                // 512*128 bf16 (k-tiled)
  float* bufA  = (float*)(W1l + 512 * 128);   // N*128
  float* bufB  = bufA + (size_t)N * 128;      // N*128
  float* bufC  = bufB + (size_t)N * 128;      // N*64
  // overlays (dead before their hosts are written):
  int* rankT = (int*)bufA;                    // EMP (dead after k_fill; bufA written later)
  int* rankE = rankT + EMP;                   // EMP
  int* cntT  = (int*)bufB;                    // N (dead after k_dinv2; bufB written later)
  int* cntE  = cntT + N;                      // N

  float* out_res  = (float*)d_out;
  float* out_attr = out_res + 2 * (size_t)ELP;
  float* out_att  = out_attr + (size_t)N * 40;

  dim3 b256(256);
  int gN = (N + 255) / 256;
  int gE4 = (EMP + 1023) / 1024;

  // CSR build + norms (+ W1 convert, independent)
  k_init<<<gN, b256, 0, stream>>>(cntT, cntE, N);
  k_cvtW<<<(512 * 128 + 255) / 256, b256, 0, stream>>>(W1, W1h, W1l, 512, 128);
  k_count<<<gE4, b256, 0, stream>>>(tp + EMP, ei + EMP, cntT, cntE, rankT, rankE, EMP);
  {
    dim3 gs(NB, 2);
    k_scanA<<<gs, b256, 0, stream>>>(cntT, cntE, bsum, N, NB);
    k_scanB<<<1, 64, 0, stream>>>(bsum, rowptrT, rowptrE, NB, N);
    k_scanC<<<gs, b256, 0, stream>>>(cntT, cntE, bsum, rowptrT, rowptrE, N, NB);
  }
  k_fill<<<gE4, b256, 0, stream>>>(tp, tp + EMP, ei, ei + EMP, ew,
                                   rowptrT, rowptrE, rankT, rankE, srcT, srcwE, EMP);
  k_dinv2<<<gN, b256, 0, stream>>>(cntT, srcwE, rowptrE, dinvT, dinvE, N);

  // conv1: h1_pre = x @ W1 (MFMA split-bf16) ; h = relu(Agg_T(h1_pre) + b1)
  k_gemm_mfma_split<<<(N + 63) / 64, b256, 0, stream>>>(x, W1h, W1l, bufA, N);
  k_gather4<128, true, false><<<(N + 7) / 8, b256, 0, stream>>>(
      bufA, rowptrT, srcT, nullptr, dinvT, bufA, b1, bufB, N);

  // conv2: h2_pre = h @ W2 ; h2 = Agg_T(h2_pre) + b2
  {
    dim3 grid(1, (N + 63) / 64);
    k_gemm<<<grid, b256, 0, stream>>>(bufB, W2, nullptr, bufA, N, 64, 128);
  }
  k_gather4<64, false, false><<<(N + 15) / 16, b256, 0, stream>>>(
      bufA, rowptrT, srcT, nullptr, dinvT, bufA, b2, bufC, N);

  // conv3/4 share aggregation: agg3 = Agg_E(h2) into bufA
  k_gather4<64, false, true><<<(N + 15) / 16, b256, 0, stream>>>(
      bufC, rowptrE, nullptr, srcwE, dinvE, bufC, nullptr, bufA, N);

  // heads
  {
    dim3 grid(1, (N + 63) / 64);
    k_gemm<<<grid, b256, 0, stream>>>(bufA, Wattr, battr, out_attr, N, 40, 64);
    k_gemm<<<grid, b256, 0, stream>>>(bufA, Watt, batt, out_att, N, 40, 64);
  }
  k_logsoftmax40<<<gN, b256, 0, stream>>>(out_attr, N);
  k_logsoftmax40<<<gN, b256, 0, stream>>>(out_att, N);

  // link prediction (h2 = bufC)
  k_linkpred4<<<(2 * ELP * 16 + 255) / 256, b256, 0, stream>>>(bufC, pos, neg, out_res, ELP);
}